// Round 6
// baseline (955.926 us; speedup 1.0000x reference)
//
#include <hip/hip_runtime.h>
#include <hip/hip_bf16.h>
#include <math.h>

// ---------------------------------------------------------------------------
// CoSADUV_NoTemporal. Round 6:
//   - k_lstm3: 32 seqs/block as two 16-seq groups per wave (ILP fills the
//     latency-bound barrier window), depth-2 gx prefetch, and fused
//     transposed store (+scene-context edge add) -> k_swap eliminated.
// ---------------------------------------------------------------------------

#define NIMG 8
#define PTOT 38400
#define PADH 136  // h row stride in fp16 elems (16B aligned: 136*2=272)

typedef _Float16 half8 __attribute__((ext_vector_type(8)));
typedef _Float16 half4 __attribute__((ext_vector_type(4)));
typedef float float4v __attribute__((ext_vector_type(4)));
typedef __attribute__((address_space(1))) const void gvoid_t;
typedef __attribute__((address_space(3))) void svoid_t;

__device__ __forceinline__ void gload16(void* s, const void* g) {
  __builtin_amdgcn_global_load_lds((gvoid_t*)g, (svoid_t*)s, 16, 0, 0);
}
// barrier that only waits for LDS ops (leaves global loads/stores in flight)
__device__ __forceinline__ void lds_barrier() {
  __asm__ volatile("s_waitcnt lgkmcnt(0)\n\ts_barrier" ::: "memory");
}

__device__ __forceinline__ float rcp_(float x) { return __builtin_amdgcn_rcpf(x); }
__device__ __forceinline__ float fsig(float x) { return rcp_(1.f + __expf(-x)); }
__device__ __forceinline__ float ftanh_(float x) {
  float e = __expf(-2.f * x);
  return 2.f * rcp_(1.f + e) - 1.f;
}

// ---- small FC: sc1[n,512], scr[n,256] from scene_ctx[n,128] ----------------
__global__ void k_fc(const float* __restrict__ ctx, const float* __restrict__ w1,
                     const float* __restrict__ b1, const float* __restrict__ wr,
                     const float* __restrict__ br, float* __restrict__ sc1,
                     float* __restrict__ scr) {
  int n = blockIdx.x;
  __shared__ float c[128];
  int t = threadIdx.x;  // 768 threads
  if (t < 128) c[t] = ctx[n * 128 + t];
  __syncthreads();
  if (t < 512) {
    float a = b1[t];
    const float* wp = w1 + t * 128;
    for (int k = 0; k < 128; k++) a += wp[k] * c[k];
    sc1[n * 512 + t] = a;
  } else {
    int j = t - 512;
    float a = br[j];
    const float* wp = wr + j * 128;
    for (int k = 0; k < 128; k++) a += wp[k] * c[k];
    scr[n * 256 + j] = a;
  }
}

// ---- pack Whh [2,512,128] f32 -> fp16 B-fragments --------------------------
// layout: [dir][wave 8][G 4][kt 4][lane 64][j 8]; frag element j =
//   B[k = kt*32 + (lane>>4)*8 + j][n = G*128 + w*16 + (lane&15)] = Whh[n][k]
__global__ void k_hfrag(const float* __restrict__ whh, _Float16* __restrict__ out) {
  int idx = blockIdx.x * 512 + threadIdx.x;  // 0..131071
  int j = idx & 7, lane = (idx >> 3) & 63, kt = (idx >> 9) & 3;
  int G = (idx >> 11) & 3, w = (idx >> 13) & 7, dir = idx >> 16;
  int n = G * 128 + w * 16 + (lane & 15);
  int k = kt * 32 + (lane >> 4) * 8 + j;
  out[idx] = (_Float16)whh[(dir * 512 + n) * 128 + k];
}

// ---- pack + row-permute Wih f32 [1024,K] -> fp16 [1024,K] ------------------
// out row n' = in row orig(n'), orig = (n'&512) + (n'&3)*128 + ((n'&511)>>2)
__global__ void k_wpermpack(const float* __restrict__ in, _Float16* __restrict__ out,
                            int K) {
  int idx = blockIdx.x * 512 + threadIdx.x;
  int np = idx / K, k = idx - np * K;
  int orig = (np & 512) + (np & 3) * 128 + ((np & 511) >> 2);
  out[(size_t)np * K + k] = (_Float16)in[(size_t)orig * K + k];
}

// ---- prep layer 1: local_feats [8,512,60,80] -> x fp16 [8,60,80,512] -------
__global__ void k_prep1(const float* __restrict__ lf, const float* __restrict__ sc1,
                        _Float16* __restrict__ x) {
  __shared__ float tile[32][33];
  int n = blockIdx.z;
  int p0 = blockIdx.x * 32;  // position in 4800
  int i0 = blockIdx.y * 32;  // channel
  const float* src = lf + (size_t)n * 512 * 4800;
  for (int r = threadIdx.y; r < 32; r += 8)
    tile[r][threadIdx.x] = src[(size_t)(i0 + r) * 4800 + p0 + threadIdx.x];
  __syncthreads();
  for (int r = threadIdx.y; r < 32; r += 8) {
    int p = p0 + r;
    int w = p % 80;
    int ch = i0 + threadIdx.x;
    float v = tile[threadIdx.x][r];
    if (w == 0 || w == 79) v += sc1[n * 512 + ch];
    x[((size_t)n * 4800 + p) * 512 + ch] = (_Float16)v;
  }
}

// ---- fp16 MFMA GEMM: C[M,1024] = A[M,K] * W'[1024,K]^T + bias --------------
// W' is row-permuted (gate-interleaved); C written contiguously; bias via
// inverse perm. grid (M/128, 8), block 256 = 4 waves (2x2 of 64x64), BK=32.
__global__ __launch_bounds__(256) void k_gemm_h(const _Float16* __restrict__ A,
                                                const _Float16* __restrict__ W,
                                                const float* __restrict__ bias,
                                                _Float16* __restrict__ C, int K) {
  __shared__ _Float16 As[128 * 32];
  __shared__ _Float16 Bs[128 * 32];
  int bm = blockIdx.x * 128, bn = blockIdx.y * 128;
  int tid = threadIdx.x;
  int w = tid >> 6, lane = tid & 63;
  int ln = lane & 15, quad = lane >> 4;
  int Wm = (w >> 1) * 64, Wn = (w & 1) * 64;
  int srow = w * 16 + (lane >> 2);   // staging row within a 64-row half
  int scol = (lane & 3) * 8;         // k-offset (8 halves = 16 B)
  const _Float16* Ap0 = A + (size_t)(bm + srow) * K + scol;
  const _Float16* Ap1 = A + (size_t)(bm + 64 + srow) * K + scol;
  const _Float16* Bp0 = W + (size_t)(bn + srow) * K + scol;
  const _Float16* Bp1 = W + (size_t)(bn + 64 + srow) * K + scol;
  _Float16* sA0 = As + (w * 16) * 32;
  _Float16* sA1 = As + (64 + w * 16) * 32;
  _Float16* sB0 = Bs + (w * 16) * 32;
  _Float16* sB1 = Bs + (64 + w * 16) * 32;

  float4v acc[4][4];
#pragma unroll
  for (int i = 0; i < 4; i++)
#pragma unroll
    for (int j = 0; j < 4; j++) acc[i][j] = (float4v){0.f, 0.f, 0.f, 0.f};

  for (int k0 = 0; k0 < K; k0 += 32) {
    gload16(sA0, Ap0 + k0);
    gload16(sA1, Ap1 + k0);
    gload16(sB0, Bp0 + k0);
    gload16(sB1, Bp1 + k0);
    __syncthreads();
    const _Float16* ar = As + (Wm + ln) * 32 + quad * 8;
    const _Float16* br = Bs + (Wn + ln) * 32 + quad * 8;
    half8 af[4], bf_[4];
#pragma unroll
    for (int mt = 0; mt < 4; mt++) af[mt] = *(const half8*)(ar + mt * 512);
#pragma unroll
    for (int nt = 0; nt < 4; nt++) bf_[nt] = *(const half8*)(br + nt * 512);
#pragma unroll
    for (int mt = 0; mt < 4; mt++)
#pragma unroll
      for (int nt = 0; nt < 4; nt++)
        acc[mt][nt] = __builtin_amdgcn_mfma_f32_16x16x32_f16(af[mt], bf_[nt],
                                                             acc[mt][nt], 0, 0, 0);
    __syncthreads();
  }
#pragma unroll
  for (int nt = 0; nt < 4; nt++) {
    int col = bn + Wn + nt * 16 + ln;  // permuted (interleaved) column
    int orig = (col & 512) + (col & 3) * 128 + ((col & 511) >> 2);
    float bv = bias[orig];
#pragma unroll
    for (int mt = 0; mt < 4; mt++) {
      size_t rbase = (size_t)(bm + Wm + mt * 16 + quad * 4) * 1024 + col;
#pragma unroll
      for (int r = 0; r < 4; r++)
        C[rbase + (size_t)r * 1024] = (_Float16)(acc[mt][nt][r] + bv);
    }
  }
}

// ---- fp16 MFMA BiLSTM recurrence, 32 seqs/block (2 groups x 16) ------------
// gx: fp16 [Bq, T, 1024] gate-interleaved (dir*512 + u*4 + G)
// out: swap_mode=1 -> next-layer x[((seq/S)*T + t)*S + seq%S][256] with scr
//      added at seq%S edges; swap_mode=0 -> y[seq*T + t][256].
// grid (Bq/32, 2), block 512 = 8 waves.
__global__ __launch_bounds__(512, 2) void k_lstm3(const _Float16* __restrict__ gx,
                                                  const _Float16* __restrict__ bfr,
                                                  _Float16* __restrict__ outp,
                                                  const float* __restrict__ scr,
                                                  int T, int S, int swap_mode) {
  int dir = blockIdx.y;
  int s0 = blockIdx.x * 32;
  int tid = threadIdx.x;
  int w = tid >> 6, lane = tid & 63;
  int ln = lane & 15, quad = lane >> 4;
  int u = w * 16 + ln;  // unit 0..127

  __shared__ __align__(16) _Float16 hbuf[2][2][16 * PADH];  // [grp][pp][...]

  // resident B-fragments
  half8 bfrag[4][4];
  const _Float16* bp = bfr + ((size_t)dir * 8 + w) * 8192;
#pragma unroll
  for (int G = 0; G < 4; G++)
#pragma unroll
    for (int kt = 0; kt < 4; kt++)
      bfrag[G][kt] = *(const half8*)(bp + ((G * 4 + kt) * 64 + lane) * 8);

  for (int i = tid; i < 2 * 2 * 16 * PADH; i += 512)
    ((_Float16*)hbuf)[i] = (_Float16)0.f;

  float cst[2][4] = {};
  const _Float16* gbase[2];
  _Float16* ob[2][4];
  float scrv[2][4];
  size_t sstride = (size_t)T * 1024;
  size_t ostride = (size_t)(swap_mode ? S : 1) * 256;
#pragma unroll
  for (int g = 0; g < 2; g++) {
    int srow = s0 + g * 16 + quad * 4;
    gbase[g] = gx + (size_t)srow * sstride + dir * 512 + u * 4;
#pragma unroll
    for (int r = 0; r < 4; r++) {
      int seq = srow + r;
      if (swap_mode) {
        int n = seq / S, rem = seq - n * S;
        ob[g][r] = outp + ((size_t)n * T * S + rem) * 256 + dir * 128 + u;
        scrv[g][r] = (rem == 0 || rem == S - 1) ? scr[n * 256 + dir * 128 + u] : 0.f;
      } else {
        ob[g][r] = outp + (size_t)seq * T * 256 + dir * 128 + u;
        scrv[g][r] = 0.f;
      }
    }
  }

  half4 gA[2][4], gB[2][4];
  {
    int t0 = dir ? (T - 1) : 0;
    int t1 = dir ? (T - 2) : 1;
#pragma unroll
    for (int g = 0; g < 2; g++)
#pragma unroll
      for (int r = 0; r < 4; r++) {
        gA[g][r] = *(const half4*)(gbase[g] + r * sstride + (size_t)t0 * 1024);
        gB[g][r] = *(const half4*)(gbase[g] + r * sstride + (size_t)t1 * 1024);
      }
  }
  lds_barrier();

  const _Float16* hrd = &hbuf[0][0][ln * PADH + quad * 8];
  const int grpoff = 2 * 16 * PADH;  // _Float16 elems between groups

  auto step = [&](half4 (&gg)[2][4], int st, half4 (&gp)[2][4]) {
    int t = dir ? (T - 1 - st) : st;
    int pb = st & 1;
    // A-frags for both groups (independent LDS streams)
    half8 af[2][4];
#pragma unroll
    for (int g = 0; g < 2; g++)
#pragma unroll
      for (int kt = 0; kt < 4; kt++)
        af[g][kt] = *(const half8*)(hrd + g * grpoff + pb * 16 * PADH + kt * 32);
    // MFMA: 2 groups x 4 gates, interleaved chains
    float4v acc[2][4];
#pragma unroll
    for (int G = 0; G < 4; G++)
#pragma unroll
      for (int g = 0; g < 2; g++) {
        float4v a = {(float)gg[g][0][G], (float)gg[g][1][G],
                     (float)gg[g][2][G], (float)gg[g][3][G]};
#pragma unroll
        for (int kt = 0; kt < 4; kt++)
          a = __builtin_amdgcn_mfma_f32_16x16x32_f16(af[g][kt], bfrag[G][kt], a, 0, 0, 0);
        acc[g][G] = a;
      }
    // prefetch t+2 into the buffer just consumed
    if (st + 2 < T) {
      int tn = dir ? (T - 3 - st) : (st + 2);
#pragma unroll
      for (int g = 0; g < 2; g++)
#pragma unroll
        for (int r = 0; r < 4; r++)
          gp[g][r] = *(const half4*)(gbase[g] + r * sstride + (size_t)tn * 1024);
    }
    // cell update + h exchange + fused store
#pragma unroll
    for (int g = 0; g < 2; g++)
#pragma unroll
      for (int r = 0; r < 4; r++) {
        float iv = fsig(acc[g][0][r]);
        float fv = fsig(acc[g][1][r]);
        float gv = ftanh_(acc[g][2][r]);
        float ov = fsig(acc[g][3][r]);
        cst[g][r] = fv * cst[g][r] + iv * gv;
        float hv = ov * ftanh_(cst[g][r]);
        hbuf[g][1 - pb][(quad * 4 + r) * PADH + u] = (_Float16)hv;
        ob[g][r][(size_t)t * ostride] = (_Float16)(hv + scrv[g][r]);
      }
    lds_barrier();
  };

  for (int st = 0; st < T; st += 2) {
    step(gA, st, gA);
    step(gB, st + 1, gB);
  }
}

// ---- head: 1x1 conv + sigmoid. y4 in [n, w, h, 256] fp16 layout ------------
__global__ void k_head(const _Float16* __restrict__ y, const float* __restrict__ cw,
                       const float* __restrict__ cb, float* __restrict__ score) {
  int wv = threadIdx.x >> 6, ln = threadIdx.x & 63;
  int o = blockIdx.x * 4 + wv;  // o = (n*80 + w)*60 + h
  const _Float16* yp = y + (size_t)o * 256;
  float a = 0.f;
  for (int c = ln; c < 256; c += 64) a += (float)yp[c] * cw[c];
  for (int off = 32; off; off >>= 1) a += __shfl_down(a, off);
  if (ln == 0) {
    int h = o % 60;
    int nw = o / 60;
    int w = nw % 80;
    int n = nw / 80;
    score[(n * 60 + h) * 80 + w] = fsig(a + cb[0]);
  }
}

// ---- bilinear upsample (align_corners=True) 60x80 -> 480x640 ---------------
__global__ void k_up(const float* __restrict__ score, float* __restrict__ out) {
  int idx = blockIdx.x * 256 + threadIdx.x;
  if (idx >= NIMG * 480 * 640) return;
  int ox = idx % 640;
  int t = idx / 640;
  int oy = t % 480;
  int n = t / 480;
  float sy = oy * (59.f / 479.f);
  float sx = ox * (79.f / 639.f);
  int y0 = min((int)sy, 58);
  int x0 = min((int)sx, 78);
  float ty = sy - (float)y0;
  float tx = sx - (float)x0;
  const float* sp = score + n * 4800;
  float v00 = sp[y0 * 80 + x0], v01 = sp[y0 * 80 + x0 + 1];
  float v10 = sp[(y0 + 1) * 80 + x0], v11 = sp[(y0 + 1) * 80 + x0 + 1];
  float v0 = v00 + (v01 - v00) * tx;
  float v1 = v10 + (v11 - v10) * tx;
  out[idx] = v0 + (v1 - v0) * ty;
}

extern "C" void kernel_launch(void* const* d_in, const int* in_sizes, int n_in,
                              void* d_out, int out_size, void* d_ws, size_t ws_size,
                              hipStream_t stream) {
  const float* lf    = (const float*)d_in[0];
  const float* ctx   = (const float*)d_in[1];
  const float* fc1w  = (const float*)d_in[2];
  const float* fc1b  = (const float*)d_in[3];
  const float* fcrw  = (const float*)d_in[4];
  const float* fcrb  = (const float*)d_in[5];
  const float* wih[4] = {(const float*)d_in[6], (const float*)d_in[9],
                         (const float*)d_in[12], (const float*)d_in[15]};
  const float* whh[4] = {(const float*)d_in[7], (const float*)d_in[10],
                         (const float*)d_in[13], (const float*)d_in[16]};
  const float* bb[4]  = {(const float*)d_in[8], (const float*)d_in[11],
                         (const float*)d_in[14], (const float*)d_in[17]};
  const float* convw = (const float*)d_in[18];
  const float* convb = (const float*)d_in[19];
  float* out = (float*)d_out;

  // workspace: floats first, then fp16 region (16B-aligned offsets)
  float* ws    = (float*)d_ws;
  float* sc1   = ws;            // 4096
  float* scr   = ws + 4096;     // 2048
  float* score = ws + 6144;     // 38400
  _Float16* hb = (_Float16*)(ws + 44544);
  _Float16* hfr  = hb;                 // 4 * 131072
  _Float16* wpk  = hb + 524288;        // 524288 + 3*262144 = 1310720
  _Float16* xbuf = hb + 1835008;       // 38400*512
  _Float16* gxh  = hb + 21495808;      // 38400*1024
  _Float16* ybuf = hb + 60817408;      // 38400*256
  _Float16* wpkL[4] = {wpk, wpk + 524288, wpk + 786432, wpk + 1048576};

  k_fc<<<NIMG, 768, 0, stream>>>(ctx, fc1w, fc1b, fcrw, fcrb, sc1, scr);
  for (int l = 0; l < 4; l++)
    k_hfrag<<<256, 512, 0, stream>>>(whh[l], hfr + (size_t)l * 131072);
  k_wpermpack<<<1024, 512, 0, stream>>>(wih[0], wpkL[0], 512);
  for (int l = 1; l < 4; l++)
    k_wpermpack<<<512, 512, 0, stream>>>(wih[l], wpkL[l], 256);
  k_prep1<<<dim3(150, 16, NIMG), dim3(32, 8), 0, stream>>>(lf, sc1, xbuf);

  // layer 1: rows (480 seqs, T=80, K=512); fused store -> x2[n,w,h] + scr@h-edge
  k_gemm_h<<<dim3(300, 8), 256, 0, stream>>>(xbuf, wpkL[0], bb[0], gxh, 512);
  k_lstm3<<<dim3(15, 2), 512, 0, stream>>>(gxh, hfr + 0 * 131072, xbuf, scr, 80, 60, 1);

  // layer 2: cols (640 seqs, T=60); fused store -> x3[n,h,w] + scr@w-edge
  k_gemm_h<<<dim3(300, 8), 256, 0, stream>>>(xbuf, wpkL[1], bb[1], gxh, 256);
  k_lstm3<<<dim3(20, 2), 512, 0, stream>>>(gxh, hfr + 1 * 131072, xbuf, scr, 60, 80, 1);

  // layer 3: rows (480 seqs, T=80); fused store -> x4[n,w,h] + scr@h-edge
  k_gemm_h<<<dim3(300, 8), 256, 0, stream>>>(xbuf, wpkL[2], bb[2], gxh, 256);
  k_lstm3<<<dim3(15, 2), 512, 0, stream>>>(gxh, hfr + 2 * 131072, xbuf, scr, 80, 60, 1);

  // layer 4: cols (640 seqs, T=60); standard store -> y[seq,t]
  k_gemm_h<<<dim3(300, 8), 256, 0, stream>>>(xbuf, wpkL[3], bb[3], gxh, 256);
  k_lstm3<<<dim3(20, 2), 512, 0, stream>>>(gxh, hfr + 3 * 131072, ybuf, scr, 60, 80, 0);

  // head + upsample
  k_head<<<PTOT / 4, 256, 0, stream>>>(ybuf, convw, convb, score);
  k_up<<<(NIMG * 480 * 640 + 255) / 256, 256, 0, stream>>>(score, out);
}

// Round 7
// 711.516 us; speedup vs baseline: 1.3435x; 1.3435x over previous
//
#include <hip/hip_runtime.h>
#include <hip/hip_bf16.h>
#include <math.h>

// ---------------------------------------------------------------------------
// CoSADUV_NoTemporal. Round 7:
//   - Recurrence reverted to the round-4 sweet spot: 16 seqs/block, 512 thr,
//     depth-2 register ping-pong gx prefetch, lgkmcnt-only barrier.
//     (8/block and 32/block both measured slower: 99.5 / 152 vs ~70 us.)
//   - Kept from round 6: fused transposed store + scene-context edge add in
//     the LSTM epilogue -> no k_swap kernels, no extra 39MB round-trip.
//   - Kept from round 5: row-permuted Wih pack so GEMM writes gx contiguously
//     in gate-interleaved order.
// ---------------------------------------------------------------------------

#define NIMG 8
#define PTOT 38400
#define PADH 136  // h row stride in fp16 elems (16B aligned: 136*2=272)

typedef _Float16 half8 __attribute__((ext_vector_type(8)));
typedef _Float16 half4 __attribute__((ext_vector_type(4)));
typedef float float4v __attribute__((ext_vector_type(4)));
typedef __attribute__((address_space(1))) const void gvoid_t;
typedef __attribute__((address_space(3))) void svoid_t;

__device__ __forceinline__ void gload16(void* s, const void* g) {
  __builtin_amdgcn_global_load_lds((gvoid_t*)g, (svoid_t*)s, 16, 0, 0);
}
// barrier that only waits for LDS ops (leaves global loads/stores in flight)
__device__ __forceinline__ void lds_barrier() {
  __asm__ volatile("s_waitcnt lgkmcnt(0)\n\ts_barrier" ::: "memory");
}

__device__ __forceinline__ float rcp_(float x) { return __builtin_amdgcn_rcpf(x); }
__device__ __forceinline__ float fsig(float x) { return rcp_(1.f + __expf(-x)); }
__device__ __forceinline__ float ftanh_(float x) {
  float e = __expf(-2.f * x);
  return 2.f * rcp_(1.f + e) - 1.f;
}

// ---- small FC: sc1[n,512], scr[n,256] from scene_ctx[n,128] ----------------
__global__ void k_fc(const float* __restrict__ ctx, const float* __restrict__ w1,
                     const float* __restrict__ b1, const float* __restrict__ wr,
                     const float* __restrict__ br, float* __restrict__ sc1,
                     float* __restrict__ scr) {
  int n = blockIdx.x;
  __shared__ float c[128];
  int t = threadIdx.x;  // 768 threads
  if (t < 128) c[t] = ctx[n * 128 + t];
  __syncthreads();
  if (t < 512) {
    float a = b1[t];
    const float* wp = w1 + t * 128;
    for (int k = 0; k < 128; k++) a += wp[k] * c[k];
    sc1[n * 512 + t] = a;
  } else {
    int j = t - 512;
    float a = br[j];
    const float* wp = wr + j * 128;
    for (int k = 0; k < 128; k++) a += wp[k] * c[k];
    scr[n * 256 + j] = a;
  }
}

// ---- pack Whh [2,512,128] f32 -> fp16 B-fragments --------------------------
// layout: [dir][wave 8][G 4][kt 4][lane 64][j 8]; frag element j =
//   B[k = kt*32 + (lane>>4)*8 + j][n = G*128 + w*16 + (lane&15)] = Whh[n][k]
__global__ void k_hfrag(const float* __restrict__ whh, _Float16* __restrict__ out) {
  int idx = blockIdx.x * 512 + threadIdx.x;  // 0..131071
  int j = idx & 7, lane = (idx >> 3) & 63, kt = (idx >> 9) & 3;
  int G = (idx >> 11) & 3, w = (idx >> 13) & 7, dir = idx >> 16;
  int n = G * 128 + w * 16 + (lane & 15);
  int k = kt * 32 + (lane >> 4) * 8 + j;
  out[idx] = (_Float16)whh[(dir * 512 + n) * 128 + k];
}

// ---- pack + row-permute Wih f32 [1024,K] -> fp16 [1024,K] ------------------
// out row n' = in row orig(n'), orig = (n'&512) + (n'&3)*128 + ((n'&511)>>2)
__global__ void k_wpermpack(const float* __restrict__ in, _Float16* __restrict__ out,
                            int K) {
  int idx = blockIdx.x * 512 + threadIdx.x;
  int np = idx / K, k = idx - np * K;
  int orig = (np & 512) + (np & 3) * 128 + ((np & 511) >> 2);
  out[(size_t)np * K + k] = (_Float16)in[(size_t)orig * K + k];
}

// ---- prep layer 1: local_feats [8,512,60,80] -> x fp16 [8,60,80,512] -------
__global__ void k_prep1(const float* __restrict__ lf, const float* __restrict__ sc1,
                        _Float16* __restrict__ x) {
  __shared__ float tile[32][33];
  int n = blockIdx.z;
  int p0 = blockIdx.x * 32;  // position in 4800
  int i0 = blockIdx.y * 32;  // channel
  const float* src = lf + (size_t)n * 512 * 4800;
  for (int r = threadIdx.y; r < 32; r += 8)
    tile[r][threadIdx.x] = src[(size_t)(i0 + r) * 4800 + p0 + threadIdx.x];
  __syncthreads();
  for (int r = threadIdx.y; r < 32; r += 8) {
    int p = p0 + r;
    int w = p % 80;
    int ch = i0 + threadIdx.x;
    float v = tile[threadIdx.x][r];
    if (w == 0 || w == 79) v += sc1[n * 512 + ch];
    x[((size_t)n * 4800 + p) * 512 + ch] = (_Float16)v;
  }
}

// ---- fp16 MFMA GEMM: C[M,1024] = A[M,K] * W'[1024,K]^T + bias --------------
// W' is row-permuted (gate-interleaved); C written contiguously; bias via
// inverse perm. grid (M/128, 8), block 256 = 4 waves (2x2 of 64x64), BK=32.
__global__ __launch_bounds__(256) void k_gemm_h(const _Float16* __restrict__ A,
                                                const _Float16* __restrict__ W,
                                                const float* __restrict__ bias,
                                                _Float16* __restrict__ C, int K) {
  __shared__ _Float16 As[128 * 32];
  __shared__ _Float16 Bs[128 * 32];
  int bm = blockIdx.x * 128, bn = blockIdx.y * 128;
  int tid = threadIdx.x;
  int w = tid >> 6, lane = tid & 63;
  int ln = lane & 15, quad = lane >> 4;
  int Wm = (w >> 1) * 64, Wn = (w & 1) * 64;
  int srow = w * 16 + (lane >> 2);   // staging row within a 64-row half
  int scol = (lane & 3) * 8;         // k-offset (8 halves = 16 B)
  const _Float16* Ap0 = A + (size_t)(bm + srow) * K + scol;
  const _Float16* Ap1 = A + (size_t)(bm + 64 + srow) * K + scol;
  const _Float16* Bp0 = W + (size_t)(bn + srow) * K + scol;
  const _Float16* Bp1 = W + (size_t)(bn + 64 + srow) * K + scol;
  _Float16* sA0 = As + (w * 16) * 32;
  _Float16* sA1 = As + (64 + w * 16) * 32;
  _Float16* sB0 = Bs + (w * 16) * 32;
  _Float16* sB1 = Bs + (64 + w * 16) * 32;

  float4v acc[4][4];
#pragma unroll
  for (int i = 0; i < 4; i++)
#pragma unroll
    for (int j = 0; j < 4; j++) acc[i][j] = (float4v){0.f, 0.f, 0.f, 0.f};

  for (int k0 = 0; k0 < K; k0 += 32) {
    gload16(sA0, Ap0 + k0);
    gload16(sA1, Ap1 + k0);
    gload16(sB0, Bp0 + k0);
    gload16(sB1, Bp1 + k0);
    __syncthreads();
    const _Float16* ar = As + (Wm + ln) * 32 + quad * 8;
    const _Float16* br = Bs + (Wn + ln) * 32 + quad * 8;
    half8 af[4], bf_[4];
#pragma unroll
    for (int mt = 0; mt < 4; mt++) af[mt] = *(const half8*)(ar + mt * 512);
#pragma unroll
    for (int nt = 0; nt < 4; nt++) bf_[nt] = *(const half8*)(br + nt * 512);
#pragma unroll
    for (int mt = 0; mt < 4; mt++)
#pragma unroll
      for (int nt = 0; nt < 4; nt++)
        acc[mt][nt] = __builtin_amdgcn_mfma_f32_16x16x32_f16(af[mt], bf_[nt],
                                                             acc[mt][nt], 0, 0, 0);
    __syncthreads();
  }
#pragma unroll
  for (int nt = 0; nt < 4; nt++) {
    int col = bn + Wn + nt * 16 + ln;  // permuted (interleaved) column
    int orig = (col & 512) + (col & 3) * 128 + ((col & 511) >> 2);
    float bv = bias[orig];
#pragma unroll
    for (int mt = 0; mt < 4; mt++) {
      size_t rbase = (size_t)(bm + Wm + mt * 16 + quad * 4) * 1024 + col;
#pragma unroll
      for (int r = 0; r < 4; r++)
        C[rbase + (size_t)r * 1024] = (_Float16)(acc[mt][nt][r] + bv);
    }
  }
}

// ---- fp16 MFMA BiLSTM recurrence, 16 seqs/block, fused transposed store ----
// gx: fp16 [Bq, T, 1024] gate-interleaved (dir*512 + u*4 + G)
// swap_mode=1: out x[((seq/S)*T + t)*S + seq%S][256] (+scr at seq%S edges)
// swap_mode=0: out y[seq*T + t][256]
// grid (Bq/16, 2), block 512 = 8 waves.
__global__ __launch_bounds__(512, 2) void k_lstm4(const _Float16* __restrict__ gx,
                                                  const _Float16* __restrict__ bfr,
                                                  _Float16* __restrict__ outp,
                                                  const float* __restrict__ scr,
                                                  int T, int S, int swap_mode) {
  int dir = blockIdx.y;
  int s0 = blockIdx.x * 16;
  int tid = threadIdx.x;
  int w = tid >> 6, lane = tid & 63;
  int ln = lane & 15, quad = lane >> 4;
  int u = w * 16 + ln;  // unit 0..127 owned by this lane

  __shared__ __align__(16) _Float16 hbuf[2][16 * PADH];

  // resident B-fragments
  half8 bfrag[4][4];
  const _Float16* bp = bfr + ((size_t)dir * 8 + w) * 8192;
#pragma unroll
  for (int G = 0; G < 4; G++)
#pragma unroll
    for (int kt = 0; kt < 4; kt++)
      bfrag[G][kt] = *(const half8*)(bp + ((G * 4 + kt) * 64 + lane) * 8);

  for (int i = tid; i < 2 * 16 * PADH; i += 512)
    ((_Float16*)hbuf)[i] = (_Float16)0.f;

  float cst[4] = {0.f, 0.f, 0.f, 0.f};
  int srow = s0 + quad * 4;
  const _Float16* gbase = gx + (size_t)srow * T * 1024 + dir * 512 + u * 4;
  size_t sstride = (size_t)T * 1024;
  size_t ostride = (size_t)(swap_mode ? S : 1) * 256;
  _Float16* ob[4];
  float scrv[4];
#pragma unroll
  for (int r = 0; r < 4; r++) {
    int seq = srow + r;
    if (swap_mode) {
      int n = seq / S, rem = seq - n * S;
      ob[r] = outp + ((size_t)n * T * S + rem) * 256 + dir * 128 + u;
      scrv[r] = (rem == 0 || rem == S - 1) ? scr[n * 256 + dir * 128 + u] : 0.f;
    } else {
      ob[r] = outp + (size_t)seq * T * 256 + dir * 128 + u;
      scrv[r] = 0.f;
    }
  }

  half4 gA[4], gB[4];
  {
    int t0 = dir ? (T - 1) : 0;
#pragma unroll
    for (int r = 0; r < 4; r++)
      gA[r] = *(const half4*)(gbase + r * sstride + (size_t)t0 * 1024);
  }
  lds_barrier();

  const _Float16* hrd = &hbuf[0][ln * PADH + quad * 8];

  auto step = [&](half4 (&gg)[4], int st, half4 (&gp)[4], bool pf) {
    int t = dir ? (T - 1 - st) : st;
    int pb = st & 1;
    half8 af[4];
#pragma unroll
    for (int kt = 0; kt < 4; kt++)
      af[kt] = *(const half8*)(hrd + pb * 16 * PADH + kt * 32);
    float4v acc[4];
#pragma unroll
    for (int G = 0; G < 4; G++) {
      float4v a = {(float)gg[0][G], (float)gg[1][G], (float)gg[2][G], (float)gg[3][G]};
#pragma unroll
      for (int kt = 0; kt < 4; kt++)
        a = __builtin_amdgcn_mfma_f32_16x16x32_f16(af[kt], bfrag[G][kt], a, 0, 0, 0);
      acc[G] = a;
    }
    if (pf) {
      int tn = dir ? (T - 3 - st) : (st + 2);
#pragma unroll
      for (int r = 0; r < 4; r++)
        gp[r] = *(const half4*)(gbase + r * sstride + (size_t)tn * 1024);
    }
#pragma unroll
    for (int r = 0; r < 4; r++) {
      float iv = fsig(acc[0][r]);
      float fv = fsig(acc[1][r]);
      float gv = ftanh_(acc[2][r]);
      float ov = fsig(acc[3][r]);
      cst[r] = fv * cst[r] + iv * gv;
      float hv = ov * ftanh_(cst[r]);
      hbuf[1 - pb][(quad * 4 + r) * PADH + u] = (_Float16)hv;
      ob[r][(size_t)t * ostride] = (_Float16)(hv + scrv[r]);
    }
    lds_barrier();
  };

  {
    int t1 = dir ? (T - 2) : 1;
#pragma unroll
    for (int r = 0; r < 4; r++)
      gB[r] = *(const half4*)(gbase + r * sstride + (size_t)t1 * 1024);
  }
  for (int st = 0; st < T; st += 2) {
    step(gA, st, gA, st + 2 < T);
    step(gB, st + 1, gB, st + 3 < T);
  }
}

// ---- head: 1x1 conv + sigmoid. y4 in [n, w, h, 256] fp16 layout ------------
__global__ void k_head(const _Float16* __restrict__ y, const float* __restrict__ cw,
                       const float* __restrict__ cb, float* __restrict__ score) {
  int wv = threadIdx.x >> 6, ln = threadIdx.x & 63;
  int o = blockIdx.x * 4 + wv;  // o = (n*80 + w)*60 + h
  const _Float16* yp = y + (size_t)o * 256;
  float a = 0.f;
  for (int c = ln; c < 256; c += 64) a += (float)yp[c] * cw[c];
  for (int off = 32; off; off >>= 1) a += __shfl_down(a, off);
  if (ln == 0) {
    int h = o % 60;
    int nw = o / 60;
    int w = nw % 80;
    int n = nw / 80;
    score[(n * 60 + h) * 80 + w] = fsig(a + cb[0]);
  }
}

// ---- bilinear upsample (align_corners=True) 60x80 -> 480x640 ---------------
__global__ void k_up(const float* __restrict__ score, float* __restrict__ out) {
  int idx = blockIdx.x * 256 + threadIdx.x;
  if (idx >= NIMG * 480 * 640) return;
  int ox = idx % 640;
  int t = idx / 640;
  int oy = t % 480;
  int n = t / 480;
  float sy = oy * (59.f / 479.f);
  float sx = ox * (79.f / 639.f);
  int y0 = min((int)sy, 58);
  int x0 = min((int)sx, 78);
  float ty = sy - (float)y0;
  float tx = sx - (float)x0;
  const float* sp = score + n * 4800;
  float v00 = sp[y0 * 80 + x0], v01 = sp[y0 * 80 + x0 + 1];
  float v10 = sp[(y0 + 1) * 80 + x0], v11 = sp[(y0 + 1) * 80 + x0 + 1];
  float v0 = v00 + (v01 - v00) * tx;
  float v1 = v10 + (v11 - v10) * tx;
  out[idx] = v0 + (v1 - v0) * ty;
}

extern "C" void kernel_launch(void* const* d_in, const int* in_sizes, int n_in,
                              void* d_out, int out_size, void* d_ws, size_t ws_size,
                              hipStream_t stream) {
  const float* lf    = (const float*)d_in[0];
  const float* ctx   = (const float*)d_in[1];
  const float* fc1w  = (const float*)d_in[2];
  const float* fc1b  = (const float*)d_in[3];
  const float* fcrw  = (const float*)d_in[4];
  const float* fcrb  = (const float*)d_in[5];
  const float* wih[4] = {(const float*)d_in[6], (const float*)d_in[9],
                         (const float*)d_in[12], (const float*)d_in[15]};
  const float* whh[4] = {(const float*)d_in[7], (const float*)d_in[10],
                         (const float*)d_in[13], (const float*)d_in[16]};
  const float* bb[4]  = {(const float*)d_in[8], (const float*)d_in[11],
                         (const float*)d_in[14], (const float*)d_in[17]};
  const float* convw = (const float*)d_in[18];
  const float* convb = (const float*)d_in[19];
  float* out = (float*)d_out;

  // workspace: floats first, then fp16 region (16B-aligned offsets)
  float* ws    = (float*)d_ws;
  float* sc1   = ws;            // 4096
  float* scr   = ws + 4096;     // 2048
  float* score = ws + 6144;     // 38400
  _Float16* hb = (_Float16*)(ws + 44544);
  _Float16* hfr  = hb;                 // 4 * 131072
  _Float16* wpk  = hb + 524288;        // 524288 + 3*262144 = 1310720
  _Float16* xbuf = hb + 1835008;       // 38400*512
  _Float16* gxh  = hb + 21495808;      // 38400*1024
  _Float16* ybuf = hb + 60817408;      // 38400*256
  _Float16* wpkL[4] = {wpk, wpk + 524288, wpk + 786432, wpk + 1048576};

  k_fc<<<NIMG, 768, 0, stream>>>(ctx, fc1w, fc1b, fcrw, fcrb, sc1, scr);
  for (int l = 0; l < 4; l++)
    k_hfrag<<<256, 512, 0, stream>>>(whh[l], hfr + (size_t)l * 131072);
  k_wpermpack<<<1024, 512, 0, stream>>>(wih[0], wpkL[0], 512);
  for (int l = 1; l < 4; l++)
    k_wpermpack<<<512, 512, 0, stream>>>(wih[l], wpkL[l], 256);
  k_prep1<<<dim3(150, 16, NIMG), dim3(32, 8), 0, stream>>>(lf, sc1, xbuf);

  // layer 1: rows (480 seqs, T=80, K=512); fused store -> x2[n,w,h] + scr@h-edge
  k_gemm_h<<<dim3(300, 8), 256, 0, stream>>>(xbuf, wpkL[0], bb[0], gxh, 512);
  k_lstm4<<<dim3(30, 2), 512, 0, stream>>>(gxh, hfr + 0 * 131072, xbuf, scr, 80, 60, 1);

  // layer 2: cols (640 seqs, T=60); fused store -> x3[n,h,w] + scr@w-edge
  k_gemm_h<<<dim3(300, 8), 256, 0, stream>>>(xbuf, wpkL[1], bb[1], gxh, 256);
  k_lstm4<<<dim3(40, 2), 512, 0, stream>>>(gxh, hfr + 1 * 131072, xbuf, scr, 60, 80, 1);

  // layer 3: rows (480 seqs, T=80); fused store -> x4[n,w,h] + scr@h-edge
  k_gemm_h<<<dim3(300, 8), 256, 0, stream>>>(xbuf, wpkL[2], bb[2], gxh, 256);
  k_lstm4<<<dim3(30, 2), 512, 0, stream>>>(gxh, hfr + 2 * 131072, xbuf, scr, 80, 60, 1);

  // layer 4: cols (640 seqs, T=60); standard store -> y[seq,t]
  k_gemm_h<<<dim3(300, 8), 256, 0, stream>>>(xbuf, wpkL[3], bb[3], gxh, 256);
  k_lstm4<<<dim3(40, 2), 512, 0, stream>>>(gxh, hfr + 3 * 131072, ybuf, scr, 60, 80, 0);

  // head + upsample
  k_head<<<PTOT / 4, 256, 0, stream>>>(ybuf, convw, convb, score);
  k_up<<<(NIMG * 480 * 640 + 255) / 256, 256, 0, stream>>>(score, out);
}

// Round 8
// 686.345 us; speedup vs baseline: 1.3928x; 1.0367x over previous
//
#include <hip/hip_runtime.h>
#include <hip/hip_bf16.h>
#include <math.h>

// ---------------------------------------------------------------------------
// CoSADUV_NoTemporal. Round 8:
//   - k_gemm2: BM=64 x BN=512 tile (grid 600x2) replaces 128x128 (300x8).
//     A-refetch factor 8 -> 2 (GEMM was HBM-bound on redundant A streams:
//     FETCH 143MB vs 20MB ideal). W stays L2-resident. 8 waves, 64x64/wave.
//   - LSTM (r4/r7 sweet spot) and everything else unchanged.
// ---------------------------------------------------------------------------

#define NIMG 8
#define PTOT 38400
#define PADH 136  // h row stride in fp16 elems (16B aligned: 136*2=272)

typedef _Float16 half8 __attribute__((ext_vector_type(8)));
typedef _Float16 half4 __attribute__((ext_vector_type(4)));
typedef float float4v __attribute__((ext_vector_type(4)));
typedef __attribute__((address_space(1))) const void gvoid_t;
typedef __attribute__((address_space(3))) void svoid_t;

__device__ __forceinline__ void gload16(void* s, const void* g) {
  __builtin_amdgcn_global_load_lds((gvoid_t*)g, (svoid_t*)s, 16, 0, 0);
}
// barrier that only waits for LDS ops (leaves global loads/stores in flight)
__device__ __forceinline__ void lds_barrier() {
  __asm__ volatile("s_waitcnt lgkmcnt(0)\n\ts_barrier" ::: "memory");
}

__device__ __forceinline__ float rcp_(float x) { return __builtin_amdgcn_rcpf(x); }
__device__ __forceinline__ float fsig(float x) { return rcp_(1.f + __expf(-x)); }
__device__ __forceinline__ float ftanh_(float x) {
  float e = __expf(-2.f * x);
  return 2.f * rcp_(1.f + e) - 1.f;
}

// ---- small FC: sc1[n,512], scr[n,256] from scene_ctx[n,128] ----------------
__global__ void k_fc(const float* __restrict__ ctx, const float* __restrict__ w1,
                     const float* __restrict__ b1, const float* __restrict__ wr,
                     const float* __restrict__ br, float* __restrict__ sc1,
                     float* __restrict__ scr) {
  int n = blockIdx.x;
  __shared__ float c[128];
  int t = threadIdx.x;  // 768 threads
  if (t < 128) c[t] = ctx[n * 128 + t];
  __syncthreads();
  if (t < 512) {
    float a = b1[t];
    const float* wp = w1 + t * 128;
    for (int k = 0; k < 128; k++) a += wp[k] * c[k];
    sc1[n * 512 + t] = a;
  } else {
    int j = t - 512;
    float a = br[j];
    const float* wp = wr + j * 128;
    for (int k = 0; k < 128; k++) a += wp[k] * c[k];
    scr[n * 256 + j] = a;
  }
}

// ---- pack Whh [2,512,128] f32 -> fp16 B-fragments --------------------------
// layout: [dir][wave 8][G 4][kt 4][lane 64][j 8]; frag element j =
//   B[k = kt*32 + (lane>>4)*8 + j][n = G*128 + w*16 + (lane&15)] = Whh[n][k]
__global__ void k_hfrag(const float* __restrict__ whh, _Float16* __restrict__ out) {
  int idx = blockIdx.x * 512 + threadIdx.x;  // 0..131071
  int j = idx & 7, lane = (idx >> 3) & 63, kt = (idx >> 9) & 3;
  int G = (idx >> 11) & 3, w = (idx >> 13) & 7, dir = idx >> 16;
  int n = G * 128 + w * 16 + (lane & 15);
  int k = kt * 32 + (lane >> 4) * 8 + j;
  out[idx] = (_Float16)whh[(dir * 512 + n) * 128 + k];
}

// ---- pack + row-permute Wih f32 [1024,K] -> fp16 [1024,K] ------------------
// out row n' = in row orig(n'), orig = (n'&512) + (n'&3)*128 + ((n'&511)>>2)
__global__ void k_wpermpack(const float* __restrict__ in, _Float16* __restrict__ out,
                            int K) {
  int idx = blockIdx.x * 512 + threadIdx.x;
  int np = idx / K, k = idx - np * K;
  int orig = (np & 512) + (np & 3) * 128 + ((np & 511) >> 2);
  out[(size_t)np * K + k] = (_Float16)in[(size_t)orig * K + k];
}

// ---- prep layer 1: local_feats [8,512,60,80] -> x fp16 [8,60,80,512] -------
__global__ void k_prep1(const float* __restrict__ lf, const float* __restrict__ sc1,
                        _Float16* __restrict__ x) {
  __shared__ float tile[32][33];
  int n = blockIdx.z;
  int p0 = blockIdx.x * 32;  // position in 4800
  int i0 = blockIdx.y * 32;  // channel
  const float* src = lf + (size_t)n * 512 * 4800;
  for (int r = threadIdx.y; r < 32; r += 8)
    tile[r][threadIdx.x] = src[(size_t)(i0 + r) * 4800 + p0 + threadIdx.x];
  __syncthreads();
  for (int r = threadIdx.y; r < 32; r += 8) {
    int p = p0 + r;
    int w = p % 80;
    int ch = i0 + threadIdx.x;
    float v = tile[threadIdx.x][r];
    if (w == 0 || w == 79) v += sc1[n * 512 + ch];
    x[((size_t)n * 4800 + p) * 512 + ch] = (_Float16)v;
  }
}

// ---- fp16 MFMA GEMM: C[M,1024] = A[M,K] * W'[1024,K]^T + bias --------------
// BM=64, BN=512, BK=32; grid (M/64, 2), block 512 = 8 waves, 64x64 per wave.
// W' row-permuted (gate-interleaved); C written contiguously; bias via
// inverse perm. A-refetch factor = N/BN = 2 (was 8 with BN=128).
__global__ __launch_bounds__(512) void k_gemm2(const _Float16* __restrict__ A,
                                               const _Float16* __restrict__ W,
                                               const float* __restrict__ bias,
                                               _Float16* __restrict__ C, int K) {
  __shared__ _Float16 As[64 * 32];    // 4 KB
  __shared__ _Float16 Bs[512 * 32];   // 32 KB
  int bm = blockIdx.x * 64, bn = blockIdx.y * 512;
  int tid = threadIdx.x;
  int w = tid >> 6, lane = tid & 63;
  int ln = lane & 15, quad = lane >> 4;
  int lrow = lane >> 2;           // 0..15 staging row within 16-row group
  int scol = (lane & 3) * 8;      // k-offset (16 B)
  const _Float16* Bp = W + (size_t)(bn + w * 64 + lrow) * K + scol;
  const _Float16* Ap = A + (size_t)(bm + w * 16 + lrow) * K + scol;  // waves 0-3
  _Float16* sB = Bs + (w * 64) * 32;
  _Float16* sA = As + (w * 16) * 32;

  float4v acc[4][4];
#pragma unroll
  for (int i = 0; i < 4; i++)
#pragma unroll
    for (int j = 0; j < 4; j++) acc[i][j] = (float4v){0.f, 0.f, 0.f, 0.f};

  for (int k0 = 0; k0 < K; k0 += 32) {
#pragma unroll
    for (int i = 0; i < 4; i++)
      gload16(sB + i * 16 * 32, Bp + (size_t)i * 16 * K + k0);
    if (w < 4) gload16(sA, Ap + k0);
    __syncthreads();
    const _Float16* ar = As + ln * 32 + quad * 8;
    const _Float16* br = Bs + (w * 64 + ln) * 32 + quad * 8;
    half8 af[4], bf_[4];
#pragma unroll
    for (int mt = 0; mt < 4; mt++) af[mt] = *(const half8*)(ar + mt * 512);
#pragma unroll
    for (int nt = 0; nt < 4; nt++) bf_[nt] = *(const half8*)(br + nt * 512);
#pragma unroll
    for (int mt = 0; mt < 4; mt++)
#pragma unroll
      for (int nt = 0; nt < 4; nt++)
        acc[mt][nt] = __builtin_amdgcn_mfma_f32_16x16x32_f16(af[mt], bf_[nt],
                                                             acc[mt][nt], 0, 0, 0);
    __syncthreads();
  }
#pragma unroll
  for (int nt = 0; nt < 4; nt++) {
    int col = bn + w * 64 + nt * 16 + ln;  // permuted (interleaved) column
    int orig = (col & 512) + (col & 3) * 128 + ((col & 511) >> 2);
    float bv = bias[orig];
#pragma unroll
    for (int mt = 0; mt < 4; mt++) {
      size_t rbase = (size_t)(bm + mt * 16 + quad * 4) * 1024 + col;
#pragma unroll
      for (int r = 0; r < 4; r++)
        C[rbase + (size_t)r * 1024] = (_Float16)(acc[mt][nt][r] + bv);
    }
  }
}

// ---- fp16 MFMA BiLSTM recurrence, 16 seqs/block, fused transposed store ----
// gx: fp16 [Bq, T, 1024] gate-interleaved (dir*512 + u*4 + G)
// swap_mode=1: out x[((seq/S)*T + t)*S + seq%S][256] (+scr at seq%S edges)
// swap_mode=0: out y[seq*T + t][256]
// grid (Bq/16, 2), block 512 = 8 waves.
__global__ __launch_bounds__(512, 2) void k_lstm4(const _Float16* __restrict__ gx,
                                                  const _Float16* __restrict__ bfr,
                                                  _Float16* __restrict__ outp,
                                                  const float* __restrict__ scr,
                                                  int T, int S, int swap_mode) {
  int dir = blockIdx.y;
  int s0 = blockIdx.x * 16;
  int tid = threadIdx.x;
  int w = tid >> 6, lane = tid & 63;
  int ln = lane & 15, quad = lane >> 4;
  int u = w * 16 + ln;  // unit 0..127 owned by this lane

  __shared__ __align__(16) _Float16 hbuf[2][16 * PADH];

  // resident B-fragments
  half8 bfrag[4][4];
  const _Float16* bp = bfr + ((size_t)dir * 8 + w) * 8192;
#pragma unroll
  for (int G = 0; G < 4; G++)
#pragma unroll
    for (int kt = 0; kt < 4; kt++)
      bfrag[G][kt] = *(const half8*)(bp + ((G * 4 + kt) * 64 + lane) * 8);

  for (int i = tid; i < 2 * 16 * PADH; i += 512)
    ((_Float16*)hbuf)[i] = (_Float16)0.f;

  float cst[4] = {0.f, 0.f, 0.f, 0.f};
  int srow = s0 + quad * 4;
  const _Float16* gbase = gx + (size_t)srow * T * 1024 + dir * 512 + u * 4;
  size_t sstride = (size_t)T * 1024;
  size_t ostride = (size_t)(swap_mode ? S : 1) * 256;
  _Float16* ob[4];
  float scrv[4];
#pragma unroll
  for (int r = 0; r < 4; r++) {
    int seq = srow + r;
    if (swap_mode) {
      int n = seq / S, rem = seq - n * S;
      ob[r] = outp + ((size_t)n * T * S + rem) * 256 + dir * 128 + u;
      scrv[r] = (rem == 0 || rem == S - 1) ? scr[n * 256 + dir * 128 + u] : 0.f;
    } else {
      ob[r] = outp + (size_t)seq * T * 256 + dir * 128 + u;
      scrv[r] = 0.f;
    }
  }

  half4 gA[4], gB[4];
  {
    int t0 = dir ? (T - 1) : 0;
#pragma unroll
    for (int r = 0; r < 4; r++)
      gA[r] = *(const half4*)(gbase + r * sstride + (size_t)t0 * 1024);
  }
  lds_barrier();

  const _Float16* hrd = &hbuf[0][ln * PADH + quad * 8];

  auto step = [&](half4 (&gg)[4], int st, half4 (&gp)[4], bool pf) {
    int t = dir ? (T - 1 - st) : st;
    int pb = st & 1;
    half8 af[4];
#pragma unroll
    for (int kt = 0; kt < 4; kt++)
      af[kt] = *(const half8*)(hrd + pb * 16 * PADH + kt * 32);
    float4v acc[4];
#pragma unroll
    for (int G = 0; G < 4; G++) {
      float4v a = {(float)gg[0][G], (float)gg[1][G], (float)gg[2][G], (float)gg[3][G]};
#pragma unroll
      for (int kt = 0; kt < 4; kt++)
        a = __builtin_amdgcn_mfma_f32_16x16x32_f16(af[kt], bfrag[G][kt], a, 0, 0, 0);
      acc[G] = a;
    }
    if (pf) {
      int tn = dir ? (T - 3 - st) : (st + 2);
#pragma unroll
      for (int r = 0; r < 4; r++)
        gp[r] = *(const half4*)(gbase + r * sstride + (size_t)tn * 1024);
    }
#pragma unroll
    for (int r = 0; r < 4; r++) {
      float iv = fsig(acc[0][r]);
      float fv = fsig(acc[1][r]);
      float gv = ftanh_(acc[2][r]);
      float ov = fsig(acc[3][r]);
      cst[r] = fv * cst[r] + iv * gv;
      float hv = ov * ftanh_(cst[r]);
      hbuf[1 - pb][(quad * 4 + r) * PADH + u] = (_Float16)hv;
      ob[r][(size_t)t * ostride] = (_Float16)(hv + scrv[r]);
    }
    lds_barrier();
  };

  {
    int t1 = dir ? (T - 2) : 1;
#pragma unroll
    for (int r = 0; r < 4; r++)
      gB[r] = *(const half4*)(gbase + r * sstride + (size_t)t1 * 1024);
  }
  for (int st = 0; st < T; st += 2) {
    step(gA, st, gA, st + 2 < T);
    step(gB, st + 1, gB, st + 3 < T);
  }
}

// ---- head: 1x1 conv + sigmoid. y4 in [n, w, h, 256] fp16 layout ------------
__global__ void k_head(const _Float16* __restrict__ y, const float* __restrict__ cw,
                       const float* __restrict__ cb, float* __restrict__ score) {
  int wv = threadIdx.x >> 6, ln = threadIdx.x & 63;
  int o = blockIdx.x * 4 + wv;  // o = (n*80 + w)*60 + h
  const _Float16* yp = y + (size_t)o * 256;
  float a = 0.f;
  for (int c = ln; c < 256; c += 64) a += (float)yp[c] * cw[c];
  for (int off = 32; off; off >>= 1) a += __shfl_down(a, off);
  if (ln == 0) {
    int h = o % 60;
    int nw = o / 60;
    int w = nw % 80;
    int n = nw / 80;
    score[(n * 60 + h) * 80 + w] = fsig(a + cb[0]);
  }
}

// ---- bilinear upsample (align_corners=True) 60x80 -> 480x640 ---------------
__global__ void k_up(const float* __restrict__ score, float* __restrict__ out) {
  int idx = blockIdx.x * 256 + threadIdx.x;
  if (idx >= NIMG * 480 * 640) return;
  int ox = idx % 640;
  int t = idx / 640;
  int oy = t % 480;
  int n = t / 480;
  float sy = oy * (59.f / 479.f);
  float sx = ox * (79.f / 639.f);
  int y0 = min((int)sy, 58);
  int x0 = min((int)sx, 78);
  float ty = sy - (float)y0;
  float tx = sx - (float)x0;
  const float* sp = score + n * 4800;
  float v00 = sp[y0 * 80 + x0], v01 = sp[y0 * 80 + x0 + 1];
  float v10 = sp[(y0 + 1) * 80 + x0], v11 = sp[(y0 + 1) * 80 + x0 + 1];
  float v0 = v00 + (v01 - v00) * tx;
  float v1 = v10 + (v11 - v10) * tx;
  out[idx] = v0 + (v1 - v0) * ty;
}

extern "C" void kernel_launch(void* const* d_in, const int* in_sizes, int n_in,
                              void* d_out, int out_size, void* d_ws, size_t ws_size,
                              hipStream_t stream) {
  const float* lf    = (const float*)d_in[0];
  const float* ctx   = (const float*)d_in[1];
  const float* fc1w  = (const float*)d_in[2];
  const float* fc1b  = (const float*)d_in[3];
  const float* fcrw  = (const float*)d_in[4];
  const float* fcrb  = (const float*)d_in[5];
  const float* wih[4] = {(const float*)d_in[6], (const float*)d_in[9],
                         (const float*)d_in[12], (const float*)d_in[15]};
  const float* whh[4] = {(const float*)d_in[7], (const float*)d_in[10],
                         (const float*)d_in[13], (const float*)d_in[16]};
  const float* bb[4]  = {(const float*)d_in[8], (const float*)d_in[11],
                         (const float*)d_in[14], (const float*)d_in[17]};
  const float* convw = (const float*)d_in[18];
  const float* convb = (const float*)d_in[19];
  float* out = (float*)d_out;

  // workspace: floats first, then fp16 region (16B-aligned offsets)
  float* ws    = (float*)d_ws;
  float* sc1   = ws;            // 4096
  float* scr   = ws + 4096;     // 2048
  float* score = ws + 6144;     // 38400
  _Float16* hb = (_Float16*)(ws + 44544);
  _Float16* hfr  = hb;                 // 4 * 131072
  _Float16* wpk  = hb + 524288;        // 524288 + 3*262144 = 1310720
  _Float16* xbuf = hb + 1835008;       // 38400*512
  _Float16* gxh  = hb + 21495808;      // 38400*1024
  _Float16* ybuf = hb + 60817408;      // 38400*256
  _Float16* wpkL[4] = {wpk, wpk + 524288, wpk + 786432, wpk + 1048576};

  k_fc<<<NIMG, 768, 0, stream>>>(ctx, fc1w, fc1b, fcrw, fcrb, sc1, scr);
  for (int l = 0; l < 4; l++)
    k_hfrag<<<256, 512, 0, stream>>>(whh[l], hfr + (size_t)l * 131072);
  k_wpermpack<<<1024, 512, 0, stream>>>(wih[0], wpkL[0], 512);
  for (int l = 1; l < 4; l++)
    k_wpermpack<<<512, 512, 0, stream>>>(wih[l], wpkL[l], 256);
  k_prep1<<<dim3(150, 16, NIMG), dim3(32, 8), 0, stream>>>(lf, sc1, xbuf);

  // layer 1: rows (480 seqs, T=80, K=512); fused store -> x2[n,w,h] + scr@h-edge
  k_gemm2<<<dim3(600, 2), 512, 0, stream>>>(xbuf, wpkL[0], bb[0], gxh, 512);
  k_lstm4<<<dim3(30, 2), 512, 0, stream>>>(gxh, hfr + 0 * 131072, xbuf, scr, 80, 60, 1);

  // layer 2: cols (640 seqs, T=60); fused store -> x3[n,h,w] + scr@w-edge
  k_gemm2<<<dim3(600, 2), 512, 0, stream>>>(xbuf, wpkL[1], bb[1], gxh, 256);
  k_lstm4<<<dim3(40, 2), 512, 0, stream>>>(gxh, hfr + 1 * 131072, xbuf, scr, 60, 80, 1);

  // layer 3: rows (480 seqs, T=80); fused store -> x4[n,w,h] + scr@h-edge
  k_gemm2<<<dim3(600, 2), 512, 0, stream>>>(xbuf, wpkL[2], bb[2], gxh, 256);
  k_lstm4<<<dim3(30, 2), 512, 0, stream>>>(gxh, hfr + 2 * 131072, xbuf, scr, 80, 60, 1);

  // layer 4: cols (640 seqs, T=60); standard store -> y[seq,t]
  k_gemm2<<<dim3(600, 2), 512, 0, stream>>>(xbuf, wpkL[3], bb[3], gxh, 256);
  k_lstm4<<<dim3(40, 2), 512, 0, stream>>>(gxh, hfr + 3 * 131072, ybuf, scr, 60, 80, 0);

  // head + upsample
  k_head<<<PTOT / 4, 256, 0, stream>>>(ybuf, convw, convb, score);
  k_up<<<(NIMG * 480 * 640 + 255) / 256, 256, 0, stream>>>(score, out);
}